// Round 1
// baseline (290.735 us; speedup 1.0000x reference)
//
#include <hip/hip_runtime.h>

#define DD 1024
#define NN 16
#define SS 4096
#define BBATCH 8
#define TOK (BBATCH*SS)

typedef __attribute__((ext_vector_type(8))) __bf16 bf16x8;
typedef __attribute__((ext_vector_type(4))) float f32x4;
typedef unsigned int u32;
typedef unsigned long long u64;

__device__ __forceinline__ void async16(void* lds, const void* g) {
  __builtin_amdgcn_global_load_lds(
      (const __attribute__((address_space(1))) u32*)(u64)(g),
      (__attribute__((address_space(3))) u32*)(u32)(u64)(lds), 16, 0, 0);
}

__device__ __forceinline__ float sigmoidf_(float v) {
  return 1.f / (1.f + __expf(-v));
}

// ---------------- f32 -> bf16 convert (vectorized, 8 elems/thread) ----------------
__global__ void k_cvt(const float* __restrict__ in, __bf16* __restrict__ out, int n8) {
  int i = blockIdx.x * blockDim.x + threadIdx.x;
  if (i >= n8) return;
  const float4* in4 = (const float4*)in;
  float4 a = in4[(u64)i * 2 + 0];
  float4 b = in4[(u64)i * 2 + 1];
  bf16x8 o;
  o[0] = (__bf16)a.x; o[1] = (__bf16)a.y; o[2] = (__bf16)a.z; o[3] = (__bf16)a.w;
  o[4] = (__bf16)b.x; o[5] = (__bf16)b.y; o[6] = (__bf16)b.z; o[7] = (__bf16)b.w;
  *(bf16x8*)(out + (u64)i * 8) = o;
}

// ---------------- projection: [lam|Bx](32768x32) = x_bf16 @ Wproj^T ----------------
// BM=128, BN=32, BK=32, 4 waves (256 thr). Wproj rows 0-15 = W_lambda, 16-31 = W_B.
__global__ __launch_bounds__(256)
void k_proj(const __bf16* __restrict__ xb, const __bf16* __restrict__ wp,
            const float* __restrict__ b_lambda,
            float* __restrict__ lam, float* __restrict__ bx) {
  __shared__ __align__(16) __bf16 sA[128 * 32];  // rows of 64B, 4 slots, XOR-swizzled
  __shared__ __align__(16) __bf16 sB[32 * 32];
  int tid = threadIdx.x;
  int lane = tid & 63, w = tid >> 6;
  int tok0 = blockIdx.x * 128;
  // staging source addresses (pre-swizzled: data for linear LDS slot s comes from s^(row&3))
  u64 aSrc[2];
#pragma unroll
  for (int q = 0; q < 2; ++q) {
    int u = q * 256 + tid;
    int row = u >> 2, slot = (u & 3) ^ (row & 3);
    aSrc[q] = (u64)((const char*)xb + ((u64)(tok0 + row) * DD + slot * 8) * 2);
  }
  u64 bSrc;
  {
    int u = tid;
    int row = u >> 2, slot = (u & 3) ^ (row & 3);
    bSrc = (u64)((const char*)wp + ((u64)row * DD + slot * 8) * 2);
  }
  f32x4 acc[2][2] = {};
  int r15 = lane & 15, kg = lane >> 4;
  for (int kt = 0; kt < DD / 32; ++kt) {
#pragma unroll
    for (int q = 0; q < 2; ++q)
      async16((char*)sA + (q * 256 + w * 64) * 16, (const void*)(aSrc[q] + kt * 64));
    if (tid < 128)
      async16((char*)sB + w * 1024, (const void*)(bSrc + kt * 64));
    __syncthreads();
    bf16x8 bfr[2];
#pragma unroll
    for (int nt = 0; nt < 2; ++nt) {
      int brow = nt * 16 + r15;
      bfr[nt] = *(const bf16x8*)((const char*)sB + brow * 64 + ((kg ^ (brow & 3)) << 4));
    }
#pragma unroll
    for (int mt = 0; mt < 2; ++mt) {
      int arow = w * 32 + mt * 16 + r15;
      bf16x8 af = *(const bf16x8*)((const char*)sA + arow * 64 + ((kg ^ (arow & 3)) << 4));
#pragma unroll
      for (int nt = 0; nt < 2; ++nt)
        acc[mt][nt] = __builtin_amdgcn_mfma_f32_16x16x32_bf16(af, bfr[nt], acc[mt][nt], 0, 0, 0);
    }
    __syncthreads();
  }
  // epilogue: C/D layout col=lane&15, row=(lane>>4)*4+reg
#pragma unroll
  for (int mt = 0; mt < 2; ++mt)
#pragma unroll
    for (int nt = 0; nt < 2; ++nt)
#pragma unroll
      for (int r = 0; r < 4; ++r) {
        int token = tok0 + w * 32 + mt * 16 + kg * 4 + r;
        int j = nt * 16 + r15;
        float v = acc[mt][nt][r];
        if (j < 16) lam[token * NN + j] = sigmoidf_(v + b_lambda[j]);
        else        bx[token * NN + (j - 16)] = v;
      }
}

// ---------------- chunked parallel scan: h_t = lam_t*h_{t-1} + Bx_t ----------------
// one block per (b,n); 256 threads x 16-step chunks; Hillis-Steele over (A,B) compose.
__global__ __launch_bounds__(256)
void k_scan(const float* __restrict__ lam, const float* __restrict__ bx,
            float* __restrict__ hs) {
  int b = blockIdx.x >> 4, n = blockIdx.x & 15;
  int t = threadIdx.x;
  const int CH = SS / 256;  // 16
  float lv[CH], bv[CH];
  int base = (b * SS + t * CH) * NN + n;
  float a = 1.f, bacc = 0.f;
#pragma unroll
  for (int i = 0; i < CH; ++i) {
    lv[i] = lam[base + i * NN];
    bv[i] = bx[base + i * NN];
    bacc = lv[i] * bacc + bv[i];
    a *= lv[i];
  }
  __shared__ float As[2][256], Bs[2][256];
  As[0][t] = a; Bs[0][t] = bacc;
  __syncthreads();
  int cur = 0;
  for (int off = 1; off < 256; off <<= 1) {
    float a2 = As[cur][t], b2 = Bs[cur][t];
    if (t >= off) {
      float ap = As[cur][t - off], bp = Bs[cur][t - off];
      b2 = b2 + a2 * bp;   // later ∘ earlier
      a2 = a2 * ap;
    }
    As[cur ^ 1][t] = a2; Bs[cur ^ 1][t] = b2;
    cur ^= 1;
    __syncthreads();
  }
  float h = (t == 0) ? 0.f : Bs[cur][t - 1];
#pragma unroll
  for (int i = 0; i < CH; ++i) {
    h = lv[i] * h + bv[i];
    hs[base + i * NN] = h;
  }
}

// ---------------- main fused kernel: gate GEMM + C@h + gate mul + RMSNorm ----------------
// BM=32 tokens x BN=1024 (full row) per block, BK=32, 8 waves (512 thr), 2 blocks/CU.
__global__ __launch_bounds__(512, 4)
void k_main(const __bf16* __restrict__ xb, const __bf16* __restrict__ wg,
            const float* __restrict__ hs, const float* __restrict__ wc,
            const float* __restrict__ rw, float* __restrict__ out) {
  __shared__ __align__(16) union {
    struct { __bf16 A[32 * 32]; __bf16 Bt[DD * 32]; } st;                  // 2KB + 64KB
    struct { float wcl[DD * 17]; float hsl[32 * NN]; float ss[32]; } ep;   // ~71.8KB
  } sm;
  int tid = threadIdx.x, lane = tid & 63, w = tid >> 6;
  int tok0 = blockIdx.x * 32;
  int r15 = lane & 15, kg = lane >> 4;
  // staging sources (pre-swizzled)
  u64 aSrc;
  {
    int u = tid;
    int row = u >> 2, slot = (u & 3) ^ (row & 3);
    aSrc = (u64)((const char*)xb + ((u64)(tok0 + (row & 31)) * DD + slot * 8) * 2);
  }
  u64 bSrc[8];
#pragma unroll
  for (int q = 0; q < 8; ++q) {
    int u = q * 512 + tid;
    int row = u >> 2, slot = (u & 3) ^ (row & 3);
    bSrc[q] = (u64)((const char*)wg + ((u64)row * DD + slot * 8) * 2);
  }
  f32x4 acc[2][8] = {};
  for (int kt = 0; kt < DD / 32; ++kt) {
    if (tid < 128)
      async16((char*)sm.st.A + w * 1024, (const void*)(aSrc + kt * 64));
#pragma unroll
    for (int q = 0; q < 8; ++q)
      async16((char*)sm.st.Bt + (q * 512 + w * 64) * 16, (const void*)(bSrc[q] + kt * 64));
    __syncthreads();
    bf16x8 af[2];
#pragma unroll
    for (int mt = 0; mt < 2; ++mt) {
      int arow = mt * 16 + r15;
      af[mt] = *(const bf16x8*)((const char*)sm.st.A + arow * 64 + ((kg ^ (arow & 3)) << 4));
    }
#pragma unroll
    for (int nt = 0; nt < 8; ++nt) {
      int brow = w * 128 + nt * 16 + r15;
      bf16x8 bfr = *(const bf16x8*)((const char*)sm.st.Bt + brow * 64 + ((kg ^ (brow & 3)) << 4));
#pragma unroll
      for (int mt = 0; mt < 2; ++mt)
        acc[mt][nt] = __builtin_amdgcn_mfma_f32_16x16x32_bf16(af[mt], bfr, acc[mt][nt], 0, 0, 0);
    }
    __syncthreads();
  }
  // ---- epilogue (LDS repurposed after final barrier above) ----
  for (int idx = tid; idx < DD * NN; idx += 512) {
    int d = idx >> 4, n = idx & 15;
    sm.ep.wcl[d * 17 + n] = wc[idx];
  }
  if (tid < 32 * NN) sm.ep.hsl[tid] = hs[(u64)tok0 * NN + tid];
  if (tid < 32) sm.ep.ss[tid] = 0.f;
  __syncthreads();
  float rwv[8];
#pragma unroll
  for (int nt = 0; nt < 8; ++nt) rwv[nt] = rw[w * 128 + nt * 16 + r15];
#pragma unroll
  for (int mt = 0; mt < 2; ++mt)
#pragma unroll
    for (int r = 0; r < 4; ++r) {
      int i = mt * 16 + kg * 4 + r;
      float rs = 0.f;
#pragma unroll
      for (int nt = 0; nt < 8; ++nt) {
        int j = w * 128 + nt * 16 + r15;
        float cy = 0.f;
#pragma unroll
        for (int n = 0; n < NN; ++n) cy += sm.ep.hsl[i * NN + n] * sm.ep.wcl[j * 17 + n];
        float g = sigmoidf_(acc[mt][nt][r]);
        float y = g * cy;
        acc[mt][nt][r] = y;  // overwrite in place (keeps VGPR <= 128)
        rs += y * y;
      }
#pragma unroll
      for (int m = 1; m < 16; m <<= 1) rs += __shfl_xor(rs, m, 64);
      if (r15 == 0) atomicAdd(&sm.ep.ss[i], rs);
    }
  __syncthreads();
#pragma unroll
  for (int mt = 0; mt < 2; ++mt)
#pragma unroll
    for (int r = 0; r < 4; ++r) {
      int i = mt * 16 + kg * 4 + r;
      float rstd = rsqrtf(sm.ep.ss[i] * (1.f / DD) + 1e-6f);
#pragma unroll
      for (int nt = 0; nt < 8; ++nt) {
        int j = w * 128 + nt * 16 + r15;
        out[(u64)(tok0 + i) * DD + j] = acc[mt][nt][r] * rstd * rwv[nt];
      }
    }
}

extern "C" void kernel_launch(void* const* d_in, const int* in_sizes, int n_in,
                              void* d_out, int out_size, void* d_ws, size_t ws_size,
                              hipStream_t stream) {
  (void)in_sizes; (void)n_in; (void)out_size; (void)ws_size;
  const float* x        = (const float*)d_in[0];
  const float* W_lambda = (const float*)d_in[1];
  const float* b_lambda = (const float*)d_in[2];
  const float* W_B      = (const float*)d_in[3];
  const float* W_C      = (const float*)d_in[4];
  const float* W_gate   = (const float*)d_in[5];
  const float* rms_w    = (const float*)d_in[6];
  char* ws = (char*)d_ws;
  __bf16* xb  = (__bf16*)(ws + 0);           // 67108864 B
  __bf16* wg  = (__bf16*)(ws + 67108864);    // 2097152 B
  __bf16* wp  = (__bf16*)(ws + 69206016);    // 65536 B
  float*  lam = (float*)(ws + 69271552);     // 2097152 B
  float*  bx  = (float*)(ws + 71368704);     // 2097152 B
  float*  hs  = (float*)(ws + 73465856);     // 2097152 B
  float*  out = (float*)d_out;

  k_cvt<<<TOK * DD / 8 / 256, 256, 0, stream>>>(x, xb, TOK * DD / 8);
  k_cvt<<<DD * DD / 8 / 256, 256, 0, stream>>>(W_gate, wg, DD * DD / 8);
  k_cvt<<<NN * DD / 8 / 256, 256, 0, stream>>>(W_lambda, wp, NN * DD / 8);
  k_cvt<<<NN * DD / 8 / 256, 256, 0, stream>>>(W_B, wp + NN * DD, NN * DD / 8);
  k_proj<<<TOK / 128, 256, 0, stream>>>(xb, wp, b_lambda, lam, bx);
  k_scan<<<BBATCH * NN, 256, 0, stream>>>(lam, bx, hs);
  k_main<<<TOK / 32, 512, 0, stream>>>(xb, wg, hs, W_C, rms_w, out);
}